// Round 11
// baseline (361.517 us; speedup 1.0000x reference)
//
#include <hip/hip_runtime.h>
#include <math.h>

// MaskedBalancedBCELoss — hard-negative mining via count-histogram select.
//
// R11: EPHEMERAL-BLOCK histogram pass (no grid-stride loop).
// Theory: all prior loop variants plateau at ~1.8 TB/s because iteration i+1's
// loads issue only after iteration i's data-dependent branches/atomics retire
// (per-iteration bubble ~ memory latency). Copy ubench (6.3 TB/s) uses
// loop-free waves. So: IPT=2 float4 per thread, 6400 one-shot blocks, 6
// independent loads issued up-front per thread, then the proven branchy body
// (R2-style), flush, exit. VGPR stays <=64 -> 32 waves/CU (thread-limit).
//
//   e1_hist: counts, pos_sum (f64), 4096-bin LDS u32 hist -> global hist1.
//   k5_final (1 block): k = min(3*pos, neg), boundary bin B, k_rem;
//     neg_sum = sum_{b>B} cnt[b]*mid(b) + k_rem*mid(B),
//     mid(b) = as_float((b<<19)|0x40000)  [midpoint model, absmax 0.0 in
//     R8/R9/R10]; out = (pos_sum + neg_sum) / (pos + k + 1e-6).

#define NBINS1 4096
#define IPT 2                      // float4 slots per thread
#define E_THREADS 256

struct Ctrl {
  unsigned long long pos_cnt;
  unsigned long long neg_cnt;
  unsigned long long k;
  double pos_sum;
  unsigned B;
  unsigned k_rem;
};

#define LN2F 0.69314718055994530942f

__device__ __forceinline__ float neg_loss_from(float p) {
  return -fmaxf(__log2f(1.0f - p) * LN2F, -100.0f);
}
__device__ __forceinline__ float pos_loss_from(float p) {
  return -fmaxf(__log2f(p) * LN2F, -100.0f);
}

__device__ __forceinline__ double bin_mid(unsigned b) {
  return (double)__uint_as_float((b << 19) | 0x40000u);
}

// ---------------- Kernel: ephemeral-block histogram pass -------------------
extern "C" __global__ void __launch_bounds__(E_THREADS)
e1_hist(const float* __restrict__ pred, const float* __restrict__ gt,
        const float* __restrict__ mask, unsigned* __restrict__ hist1,
        Ctrl* __restrict__ ctrl, int n4, int n) {
  __shared__ unsigned h[NBINS1];
  for (int i = threadIdx.x; i < NBINS1; i += E_THREADS) h[i] = 0u;
  __syncthreads();

  const float4* p4 = (const float4*)pred;
  const float4* g4 = (const float4*)gt;
  const float4* m4 = (const float4*)mask;

  // issue ALL loads up-front (no loop-carried dependence, wave retires after)
  int base = blockIdx.x * (E_THREADS * IPT) + threadIdx.x;
  float4 pv[IPT], gv[IPT], mv[IPT];
  bool inb[IPT];
#pragma unroll
  for (int j = 0; j < IPT; j++) {
    int i = base + j * E_THREADS;
    inb[j] = (i < n4);
    if (inb[j]) { pv[j] = p4[i]; gv[j] = g4[i]; mv[j] = m4[i]; }
    else {
      pv[j] = make_float4(0.5f, 0.5f, 0.5f, 0.5f);
      gv[j] = make_float4(0.f, 0.f, 0.f, 0.f);
      mv[j] = make_float4(0.f, 0.f, 0.f, 0.f);   // mask=0 -> no contribution
    }
  }

  unsigned pc = 0, nc = 0;
  double psum = 0.0;
#pragma unroll
  for (int j = 0; j < IPT; j++) {
    float pa[4] = {pv[j].x, pv[j].y, pv[j].z, pv[j].w};
    float ga[4] = {gv[j].x, gv[j].y, gv[j].z, gv[j].w};
    float ma[4] = {mv[j].x, mv[j].y, mv[j].z, mv[j].w};
#pragma unroll
    for (int e = 0; e < 4; e++) {
      if (ma[e] != 0.0f) {
        if (ga[e] != 0.0f) {
          pc++; psum += (double)pos_loss_from(pa[e]);
        } else {
          nc++;
          atomicAdd(&h[__float_as_uint(neg_loss_from(pa[e])) >> 19], 1u);
        }
      }
    }
  }
  // scalar tail (n % 4 != 0) — empty for this shape, generic for safety
  {
    int gtid = blockIdx.x * E_THREADS + threadIdx.x;
    int gstride = gridDim.x * E_THREADS;
    for (int i = n4 * 4 + gtid; i < n; i += gstride) {
      float p = pred[i], g = gt[i], m = mask[i];
      if (m != 0.0f) {
        if (g != 0.0f) { pc++; psum += (double)pos_loss_from(p); }
        else {
          nc++;
          atomicAdd(&h[__float_as_uint(neg_loss_from(p)) >> 19], 1u);
        }
      }
    }
  }

  // block reduce pc/nc/psum
  unsigned long long pcl = pc, ncl = nc;
  for (int off = 32; off > 0; off >>= 1) {
    pcl += __shfl_down(pcl, off);
    ncl += __shfl_down(ncl, off);
    psum += __shfl_down(psum, off);
  }
  __shared__ unsigned long long spc[4], snc[4];
  __shared__ double sps[4];
  int wv = threadIdx.x >> 6, ln = threadIdx.x & 63;
  if (ln == 0) { spc[wv] = pcl; snc[wv] = ncl; sps[wv] = psum; }
  __syncthreads();   // also completes all LDS hist atomics
  if (threadIdx.x == 0) {
    unsigned long long tp = 0, tn = 0; double ts = 0.0;
    for (int w = 0; w < 4; w++) { tp += spc[w]; tn += snc[w]; ts += sps[w]; }
    if (tp) atomicAdd(&ctrl->pos_cnt, tp);
    if (tn) atomicAdd(&ctrl->neg_cnt, tn);
    if (ts != 0.0) unsafeAtomicAdd(&ctrl->pos_sum, ts);
  }
  // flush non-empty bins to global
  for (int i = threadIdx.x; i < NBINS1; i += E_THREADS) {
    unsigned c = h[i];
    if (c) atomicAdd(&hist1[i], c);
  }
}

// ---------- Kernel 5: select + midpoint neg_sum + output (1 block) ---------
extern "C" __global__ void __launch_bounds__(256)
k5_final(const unsigned* __restrict__ hist1, Ctrl* __restrict__ ctrl,
         float* __restrict__ out) {
  const int T = 256, CH = NBINS1 / T;  // 16 bins per thread
  __shared__ unsigned long long sarr[T];
  __shared__ unsigned long long sk;
  __shared__ unsigned sB, skrem;
  __shared__ double sred[4];
  int t = threadIdx.x;
  int wv = t >> 6, ln = t & 63;

  unsigned cnt[CH];
  unsigned long long tot = 0;
  for (int j = 0; j < CH; j++) { cnt[j] = hist1[t * CH + j]; tot += cnt[j]; }
  sarr[t] = tot;
  if (t == 0) {
    sB = 0xFFFFFFFFu; skrem = 0u;
    unsigned long long pos = ctrl->pos_cnt, negtot = ctrl->neg_cnt;
    unsigned long long k = 0;
    if (pos > 0) {               // FALLBACK_NEG=0 when pos==0
      k = pos * 3ull;            // floor(pos*3.0), exact in integer
      if (k > negtot) k = negtot;
    }
    ctrl->k = k;
    sk = k;
  }
  __syncthreads();
  // inclusive suffix scan: sarr[t] = sum over threads >= t
  for (int off = 1; off < T; off <<= 1) {
    unsigned long long v = (t + off < T) ? sarr[t + off] : 0ull;
    __syncthreads();
    sarr[t] += v;
    __syncthreads();
  }
  unsigned long long k = sk;
  if (k > 0) {
    unsigned long long above = sarr[t] - tot;
    if (above < k && sarr[t] >= k) {
      unsigned long long cum = above;
      for (int j = CH - 1; j >= 0; j--) {
        if (cum + (unsigned long long)cnt[j] >= k) {
          sB = (unsigned)(t * CH + j);
          skrem = (unsigned)(k - cum);
          break;
        }
        cum += cnt[j];
      }
    }
  }
  __syncthreads();
  unsigned B = sB;

  // neg_sum (midpoint model): each thread sums its own bins above B
  double s = 0.0;
  if (B != 0xFFFFFFFFu) {
    for (int j = 0; j < CH; j++) {
      unsigned bi = (unsigned)(t * CH + j);
      if (bi > B && cnt[j]) s += (double)cnt[j] * bin_mid(bi);
    }
  }
  for (int off = 32; off > 0; off >>= 1) s += __shfl_down(s, off);
  if (ln == 0) sred[wv] = s;
  __syncthreads();
  if (t == 0) {
    double neg_sum = sred[0] + sred[1] + sred[2] + sred[3];
    if (skrem > 0 && B != 0xFFFFFFFFu)
      neg_sum += (double)skrem * bin_mid(B);
    double denom = (double)ctrl->pos_cnt + (double)k + 1e-6;
    out[0] = (float)((ctrl->pos_sum + neg_sum) / denom);
  }
}

// ---------------------------------------------------------------------------
extern "C" void kernel_launch(void* const* d_in, const int* in_sizes, int n_in,
                              void* d_out, int out_size, void* d_ws, size_t ws_size,
                              hipStream_t stream) {
  const float* pred = (const float*)d_in[0];
  const float* gt   = (const float*)d_in[1];
  const float* mask = (const float*)d_in[2];
  float* out = (float*)d_out;
  int n = in_sizes[0];
  int n4 = n / 4;
  char* ws = (char*)d_ws;

  // layout: ctrl@0 (64B), hist1@256 (16KB) -> zero first 16640 bytes
  const size_t HIST1_OFF = 256;
  const size_t ZERO_BYTES = HIST1_OFF + NBINS1 * sizeof(unsigned);   // 16640

  Ctrl* ctrl = (Ctrl*)ws;
  unsigned* hist1 = (unsigned*)(ws + HIST1_OFF);

  int blocks = (n4 + E_THREADS * IPT - 1) / (E_THREADS * IPT);
  if (blocks < 1) blocks = 1;

  hipMemsetAsync(d_ws, 0, ZERO_BYTES, stream);
  e1_hist<<<blocks, E_THREADS, 0, stream>>>(pred, gt, mask, hist1, ctrl, n4, n);
  k5_final<<<1, 256, 0, stream>>>(hist1, ctrl, out);
}

// Round 12
// 231.970 us; speedup vs baseline: 1.5585x; 1.5585x over previous
//
#include <hip/hip_runtime.h>
#include <math.h>

// MaskedBalancedBCELoss — hard-negative mining via count-histogram select.
//
// R12: R10 pipeline (best: 198µs) with ONE change: grid 1024 -> 2048.
// Rationale: k1 at grid 1024 = 4 blocks/CU = ~12 waves/CU (34-38% occupancy),
// but LDS 16.9KB/block permits 9 blocks/CU — occupancy was grid-capped.
// 2048 blocks -> 8 blocks/CU -> 32 waves/CU (thread limit), doubling
// outstanding loads per CU for latency hiding. Kernel code byte-identical
// (VGPR-16 codegen preserved; R9 showed fusing anything regresses codegen,
// R11 showed ephemeral blocks pay unamortized per-block costs).
//
//   k1_hist: stream pred/gt/mask -> pos/neg counts, pos_sum (f64),
//     4096-bin LDS u32 count hist (bin = float_bits(loss)>>19) -> hist1.
//   k5_final (1 block): k = min(3*pos, neg), boundary bin B, k_rem;
//     neg_sum = sum_{b>B} cnt[b]*mid(b) + k_rem*mid(B),
//     mid(b) = as_float((b<<19)|0x40000)  [midpoint model; absmax 0.0 in
//     R8/R9/R10]; out = (pos_sum + neg_sum) / (pos + k + 1e-6).

#define NBINS1 4096
#define K1_BLOCKS 2048

struct Ctrl {
  unsigned long long pos_cnt;
  unsigned long long neg_cnt;
  unsigned long long k;
  double pos_sum;
  unsigned B;
  unsigned k_rem;
};

#define LN2F 0.69314718055994530942f

__device__ __forceinline__ float neg_loss_from(float p) {
  return -fmaxf(__log2f(1.0f - p) * LN2F, -100.0f);
}
__device__ __forceinline__ float pos_loss_from(float p) {
  return -fmaxf(__log2f(p) * LN2F, -100.0f);
}

__device__ __forceinline__ double bin_mid(unsigned b) {
  return (double)__uint_as_float((b << 19) | 0x40000u);
}

// ---------------- Kernel 1: reductions + level-1 histogram -----------------
// Byte-identical to R10's k1 (89µs @ grid 1024); only the launch grid changes.
extern "C" __global__ void __launch_bounds__(256)
k1_hist(const float* __restrict__ pred, const float* __restrict__ gt,
        const float* __restrict__ mask, unsigned* __restrict__ hist1,
        Ctrl* __restrict__ ctrl, int n4, int n) {
  __shared__ unsigned h[NBINS1];
  for (int i = threadIdx.x; i < NBINS1; i += blockDim.x) h[i] = 0u;
  __syncthreads();

  unsigned pc = 0, nc = 0;
  double psum = 0.0;
  const float4* p4 = (const float4*)pred;
  const float4* g4 = (const float4*)gt;
  const float4* m4 = (const float4*)mask;
  int gtid = blockIdx.x * blockDim.x + threadIdx.x;
  int stride = gridDim.x * blockDim.x;

  for (int i = gtid; i < n4; i += stride) {
    float4 pv = p4[i], gv = g4[i], mv = m4[i];
    float pa[4] = {pv.x, pv.y, pv.z, pv.w};
    float ga[4] = {gv.x, gv.y, gv.z, gv.w};
    float ma[4] = {mv.x, mv.y, mv.z, mv.w};
#pragma unroll
    for (int j = 0; j < 4; j++) {
      if (ma[j] != 0.0f) {
        if (ga[j] != 0.0f) {
          pc++; psum += (double)pos_loss_from(pa[j]);
        } else {
          nc++;
          atomicAdd(&h[__float_as_uint(neg_loss_from(pa[j])) >> 19], 1u);
        }
      }
    }
  }
  // scalar tail (n % 4 != 0)
  for (int i = n4 * 4 + gtid; i < n; i += stride) {
    float p = pred[i], g = gt[i], m = mask[i];
    if (m != 0.0f) {
      if (g != 0.0f) { pc++; psum += (double)pos_loss_from(p); }
      else {
        nc++;
        atomicAdd(&h[__float_as_uint(neg_loss_from(p)) >> 19], 1u);
      }
    }
  }

  // block reduce pc/nc/psum
  unsigned long long pcl = pc, ncl = nc;
  for (int off = 32; off > 0; off >>= 1) {
    pcl += __shfl_down(pcl, off);
    ncl += __shfl_down(ncl, off);
    psum += __shfl_down(psum, off);
  }
  __shared__ unsigned long long spc[4], snc[4];
  __shared__ double sps[4];
  int wv = threadIdx.x >> 6, ln = threadIdx.x & 63;
  if (ln == 0) { spc[wv] = pcl; snc[wv] = ncl; sps[wv] = psum; }
  __syncthreads();   // also ensures all LDS histogram atomics are complete
  if (threadIdx.x == 0) {
    unsigned long long tp = 0, tn = 0; double ts = 0.0;
    for (int w = 0; w < 4; w++) { tp += spc[w]; tn += snc[w]; ts += sps[w]; }
    atomicAdd(&ctrl->pos_cnt, tp);
    atomicAdd(&ctrl->neg_cnt, tn);
    unsafeAtomicAdd(&ctrl->pos_sum, ts);
  }
  // flush LDS histogram to global (skip empty bins)
  for (int i = threadIdx.x; i < NBINS1; i += blockDim.x) {
    unsigned c = h[i];
    if (c) atomicAdd(&hist1[i], c);
  }
}

// ---------- Kernel 5: select + midpoint neg_sum + output (1 block) ---------
extern "C" __global__ void __launch_bounds__(256)
k5_final(const unsigned* __restrict__ hist1, Ctrl* __restrict__ ctrl,
         float* __restrict__ out) {
  const int T = 256, CH = NBINS1 / T;  // 16 bins per thread
  __shared__ unsigned long long sarr[T];
  __shared__ unsigned long long sk;
  __shared__ unsigned sB, skrem;
  __shared__ double sred[4];
  int t = threadIdx.x;
  int wv = t >> 6, ln = t & 63;

  unsigned cnt[CH];
  unsigned long long tot = 0;
  for (int j = 0; j < CH; j++) { cnt[j] = hist1[t * CH + j]; tot += cnt[j]; }
  sarr[t] = tot;
  if (t == 0) {
    sB = 0xFFFFFFFFu; skrem = 0u;
    unsigned long long pos = ctrl->pos_cnt, negtot = ctrl->neg_cnt;
    unsigned long long k = 0;
    if (pos > 0) {               // FALLBACK_NEG=0 when pos==0
      k = pos * 3ull;            // floor(pos*3.0), exact in integer
      if (k > negtot) k = negtot;
    }
    ctrl->k = k;
    sk = k;
  }
  __syncthreads();
  // inclusive suffix scan: sarr[t] = sum over threads >= t
  for (int off = 1; off < T; off <<= 1) {
    unsigned long long v = (t + off < T) ? sarr[t + off] : 0ull;
    __syncthreads();
    sarr[t] += v;
    __syncthreads();
  }
  unsigned long long k = sk;
  if (k > 0) {
    unsigned long long above = sarr[t] - tot;
    if (above < k && sarr[t] >= k) {
      unsigned long long cum = above;
      for (int j = CH - 1; j >= 0; j--) {
        if (cum + (unsigned long long)cnt[j] >= k) {
          sB = (unsigned)(t * CH + j);
          skrem = (unsigned)(k - cum);
          break;
        }
        cum += cnt[j];
      }
    }
  }
  __syncthreads();
  unsigned B = sB;

  // neg_sum (midpoint model): each thread sums its own bins above B
  double s = 0.0;
  if (B != 0xFFFFFFFFu) {
    for (int j = 0; j < CH; j++) {
      unsigned bi = (unsigned)(t * CH + j);
      if (bi > B && cnt[j]) s += (double)cnt[j] * bin_mid(bi);
    }
  }
  for (int off = 32; off > 0; off >>= 1) s += __shfl_down(s, off);
  if (ln == 0) sred[wv] = s;
  __syncthreads();
  if (t == 0) {
    double neg_sum = sred[0] + sred[1] + sred[2] + sred[3];
    if (skrem > 0 && B != 0xFFFFFFFFu)
      neg_sum += (double)skrem * bin_mid(B);
    double denom = (double)ctrl->pos_cnt + (double)k + 1e-6;
    out[0] = (float)((ctrl->pos_sum + neg_sum) / denom);
  }
}

// ---------------------------------------------------------------------------
extern "C" void kernel_launch(void* const* d_in, const int* in_sizes, int n_in,
                              void* d_out, int out_size, void* d_ws, size_t ws_size,
                              hipStream_t stream) {
  const float* pred = (const float*)d_in[0];
  const float* gt   = (const float*)d_in[1];
  const float* mask = (const float*)d_in[2];
  float* out = (float*)d_out;
  int n = in_sizes[0];
  int n4 = n / 4;
  char* ws = (char*)d_ws;

  // layout: ctrl@0 (64B), hist1@256 (16KB) -> zero first 16640 bytes
  const size_t HIST1_OFF = 256;
  const size_t ZERO_BYTES = HIST1_OFF + NBINS1 * sizeof(unsigned);   // 16640

  Ctrl* ctrl = (Ctrl*)ws;
  unsigned* hist1 = (unsigned*)(ws + HIST1_OFF);

  hipMemsetAsync(d_ws, 0, ZERO_BYTES, stream);
  k1_hist<<<K1_BLOCKS, 256, 0, stream>>>(pred, gt, mask, hist1, ctrl, n4, n);
  k5_final<<<1, 256, 0, stream>>>(hist1, ctrl, out);
}